// Round 13
// baseline (62.149 us; speedup 1.0000x reference)
//
#include <hip/hip_runtime.h>
#include <hip/hip_bf16.h>

#define NROWS 8192
#define DIM 256
#define NSPLIT 32
#define JSPAN (NROWS / NSPLIT)   /* 256 cols per block */
#define NGRP (JSPAN / 16)        /* 16 groups of 16 cols per wave */
#define RPW 64                   /* rows per wave (A stationary) */
#define RPB 256                  /* rows per block (4 waves) */
#define GRP_BYTES 4096           /* 16 cols x 256 B fp8, K-major-grouped */

typedef float f32x4 __attribute__((ext_vector_type(4)));
typedef long i64frag;            /* 8 fp8 = one MFMA operand */

#define NEG_LOG2E -1.4426950408889634f
#define NEG_LN2   -0.6931471805599453f

// ---- Kernel 1: L2-normalize rows, fp32 -> fp8 e4m3; zero accums ----
// En: row-major fp8 (256B/row), scaled by -log2(e) so GEMM acc = -log2e*sim
//     -> exp(-sim) = exp2(acc).
// Qn: LANE-ORDERED K-MAJOR-GROUPED fp8. Group g = cols [16g,16g+16), 4KB.
//     Chunk kk (512B) = the 16 cols' K-slice [kk*32,kk*32+32), stored in MFMA
//     fragment lane order: byte(col c, k=kk*32+lks*8+e) at
//       g*4096 + kk*512 + lks*128 + c*8 + e.
//     => DMA is a contiguous identity copy AND the ds_read is lane*8 +
//     immediate (conflict-free, zero address VALU).
__global__ __launch_bounds__(256) void k_normalize_all(const float* __restrict__ emb,
                                                       const float* __restrict__ qry,
                                                       unsigned char* __restrict__ En,
                                                       unsigned char* __restrict__ Qn,
                                                       float* __restrict__ rowsum,
                                                       float* __restrict__ out) {
    if (blockIdx.x < 8)
        reinterpret_cast<float4*>(rowsum)[blockIdx.x * 256 + threadIdx.x] =
            float4{0.f, 0.f, 0.f, 0.f};
    if (blockIdx.x == 8 && threadIdx.x == 0) out[0] = 0.f;

    const int gr   = blockIdx.x * 4 + (threadIdx.x >> 6);
    const int lane = threadIdx.x & 63;
    const bool isE = (gr < NROWS);
    const float* in = isE ? emb : qry;
    const int row   = isE ? gr : gr - NROWS;
    const float scale = isE ? NEG_LOG2E : 1.0f;

    const float4 v = reinterpret_cast<const float4*>(in + (size_t)row * DIM)[lane];
    float ss = v.x * v.x + v.y * v.y + v.z * v.z + v.w * v.w;
#pragma unroll
    for (int m = 32; m >= 1; m >>= 1) ss += __shfl_xor(ss, m, 64);
    const float inv = scale / fmaxf(sqrtf(ss), 1e-8f);

    // Pack 4 fp8 e4m3 bytes (this lane's k = lane*4 .. lane*4+4).
    int pk = __builtin_amdgcn_cvt_pk_fp8_f32(v.x * inv, v.y * inv, 0, false);
    pk     = __builtin_amdgcn_cvt_pk_fp8_f32(v.z * inv, v.w * inv, pk, true);

    if (isE) {
        *reinterpret_cast<int*>(En + (size_t)row * 256 + lane * 4) = pk;
    } else {
        const int g = row >> 4, c = row & 15;
        // k = lane*4: chunk kk = lane>>3, lks = (lane>>1)&3, e-base = (lane&1)*4.
        *reinterpret_cast<int*>(Qn + (size_t)g * GRP_BYTES + (lane >> 3) * 512
                                + ((lane >> 1) & 3) * 128 + c * 8 + (lane & 1) * 4) = pk;
    }
}

// Stage one 16-col fp8 group (4 KB) into a wave-private LDS buffer:
// 4 DMAs, each a CONTIGUOUS 1KB identity copy (lane l -> src+l*16, dst+l*16).
__device__ __forceinline__ void stage_group(const char* qlane, char* wdst) {
#pragma unroll
    for (int i = 0; i < 4; ++i)
        __builtin_amdgcn_global_load_lds(
            (const __attribute__((address_space(1))) void*)(qlane + i * 1024),
            (__attribute__((address_space(3))) void*)(wdst + i * 1024), 16, 0, 0);
}

// ---- Kernel 2: fused fp8 sim-GEMM + row sum of exp(-s) ----
// ZERO barriers. 1024 blocks (4/CU), 4 waves/block, TARGET 16 waves/CU
// (fp8 halves the A-fragment file to 64 VGPR; launch_bounds(256,4) caps 128).
// Each wave: 64 stationary A-rows, private 2x4KB LDS double buffer, depth-2
// prefetch with counted vmcnt(4); stage(p+2) issued after the MFMA loop
// (lgkmcnt(0) guard - it overwrites the buffer just read).
__global__ __launch_bounds__(256, 4) void k_simlse(const unsigned char* __restrict__ En,
                                                   const unsigned char* __restrict__ Qn,
                                                   float* __restrict__ rowsum,
                                                   float* __restrict__ pickv) {
    __shared__ char lds[4][2][GRP_BYTES];   // [wave][buf] -> 32 KB/block
    const int bx   = blockIdx.x;
    const int ib   = bx >> 5;
    const int jq   = bx & 31;
    const int tid  = threadIdx.x;
    const int lane = tid & 63;
    const int w    = tid >> 6;
    const int l15  = lane & 15;
    const int lks  = lane >> 4;          // k-subsegment 0..3
    const int i0w  = ib * RPB + w * RPW;

    char* wbase = &lds[w][0][0];
    const char* rdbase = wbase + lane * 8;   // lane-ordered chunks: identity

    // A fragments: 64 rows x K=256 fp8 -> a[4][8] (8B each = 64 VGPR total).
    // fp8 16x16x32 A layout: row = lane&15, k = kk*32 + (lane>>4)*8 + e.
    i64frag a[4][8];
    {
        const unsigned char* ab = En + (size_t)(i0w + l15) * 256 + lks * 8;
#pragma unroll
        for (int mi = 0; mi < 4; ++mi)
#pragma unroll
            for (int kk = 0; kk < 8; ++kk)
                a[mi][kk] = *reinterpret_cast<const i64frag*>(ab + mi * 16 * 256 + kk * 32);
    }

    float racc[4][4];
#pragma unroll
    for (int mi = 0; mi < 4; ++mi)
#pragma unroll
        for (int r = 0; r < 4; ++r) racc[mi][r] = 0.0f;

    const int jq0 = jq * JSPAN;
    // Per-lane DMA source: contiguous identity copy, +4KB per group.
    const char* qlane = (const char*)Qn + (size_t)jq0 * 256 + (size_t)lane * 16;
    const char* qnext = qlane + 2 * GRP_BYTES;   // source for group p+2

    auto step = [&](int p, int rdoff, const char* stsrc) {
        // Counted wait: group p's 4 DMAs (issued two steps ago) done; the 4
        // newest (group p+1) stay in flight. Tail drains to 0.
        if (p == NGRP - 1) asm volatile("s_waitcnt vmcnt(0)" ::: "memory");
        else               asm volatile("s_waitcnt vmcnt(4)" ::: "memory");

        f32x4 acc[4];
#pragma unroll
        for (int mi = 0; mi < 4; ++mi) acc[mi] = f32x4{0.f, 0.f, 0.f, 0.f};

        // Interleaved b-load + MFMA (keeps ~2 b regs live; compiler inserts
        // fine-grained lgkmcnt). b = 8 fp8 at lane*8 + kk*512: conflict-free.
        __builtin_amdgcn_s_setprio(1);
#pragma unroll
        for (int kk = 0; kk < 8; ++kk) {
            const i64frag b = *reinterpret_cast<const i64frag*>(rdbase + rdoff + kk * 512);
#pragma unroll
            for (int mi = 0; mi < 4; ++mi)
                acc[mi] = __builtin_amdgcn_mfma_f32_16x16x32_fp8_fp8(
                    a[mi][kk], b, acc[mi], 0, 0, 0);
        }
        __builtin_amdgcn_s_setprio(0);

        // All ds_reads of this buffer are consumed; drain (free) then
        // overwrite it with group p+2. DMA issue hides under the epilogue.
        asm volatile("s_waitcnt lgkmcnt(0)" ::: "memory");
        if (p + 2 < NGRP) stage_group(stsrc, wbase + rdoff);

        // Epilogue. acc = -log2e*s; exp(-s) = exp2(acc).
        // C/D layout: col = lane&15, row = (lane>>4)*4 + r.
        const int grpbase = jq0 + p * 16;
        const bool spec = (grpbase <= i0w + RPW) && (grpbase + 16 > i0w);
        if (!spec) {
#pragma unroll
            for (int mi = 0; mi < 4; ++mi)
#pragma unroll
                for (int r = 0; r < 4; ++r)
                    racc[mi][r] += __builtin_amdgcn_exp2f(acc[mi][r]);
        } else {
            const int jg = grpbase + l15;
#pragma unroll
            for (int mi = 0; mi < 4; ++mi) {
                const int ig0 = i0w + mi * 16 + lks * 4;
#pragma unroll
                for (int r = 0; r < 4; ++r) {
                    const float e  = __builtin_amdgcn_exp2f(acc[mi][r]);
                    const int   ig = ig0 + r;
                    racc[mi][r] += (jg == ig) ? 0.0f : e;
                    const int pc = (ig == NROWS - 1) ? (NROWS - 2) : (ig + 1);
                    if (jg == pc) pickv[ig] = acc[mi][r] * NEG_LN2;  // recover s
                }
            }
        }
    };

    // Prologue: stage groups 0 (buf0) and 1 (buf1).
    stage_group(qlane, wbase);
    stage_group(qlane + GRP_BYTES, wbase + GRP_BYTES);

    // Unrolled x2: buffer parity compile-time (even group -> buf0).
    for (int pp = 0; pp < NGRP; pp += 2) {
        step(pp,     0,         qnext);               // read buf0, stage p+2 -> buf0
        step(pp + 1, GRP_BYTES, qnext + GRP_BYTES);   // read buf1, stage p+3 -> buf1
        qnext += 2 * GRP_BYTES;
    }

    // Reduce row partials across the 16 col-lanes, one atomicAdd per row.
#pragma unroll
    for (int mi = 0; mi < 4; ++mi)
#pragma unroll
        for (int r = 0; r < 4; ++r) {
            float v = racc[mi][r];
            v += __shfl_xor(v, 1, 64);
            v += __shfl_xor(v, 2, 64);
            v += __shfl_xor(v, 4, 64);
            v += __shfl_xor(v, 8, 64);
            if (l15 == 0) atomicAdd(&rowsum[i0w + mi * 16 + lks * 4 + r], v);
        }
}

// ---- Kernel 3: final reduce, 16 blocks, one atomicAdd each (out pre-zeroed) ----
__global__ __launch_bounds__(256) void k_finalize(const float* __restrict__ rowsum,
                                                  const float* __restrict__ pickv,
                                                  float* __restrict__ out) {
    __shared__ float red[4];
    const int base = blockIdx.x * 512;
    float s = 0.0f;
#pragma unroll
    for (int it = 0; it < 2; ++it) {
        const int i = base + it * 256 + threadIdx.x;
        s += __logf(rowsum[i]) + pickv[i];
    }
#pragma unroll
    for (int m = 32; m >= 1; m >>= 1) s += __shfl_xor(s, m, 64);
    if ((threadIdx.x & 63) == 0) red[threadIdx.x >> 6] = s;
    __syncthreads();
    if (threadIdx.x == 0)
        atomicAdd(out, (red[0] + red[1] + red[2] + red[3]) * (1.0f / (float)NROWS));
}

extern "C" void kernel_launch(void* const* d_in, const int* in_sizes, int n_in,
                              void* d_out, int out_size, void* d_ws, size_t ws_size,
                              hipStream_t stream) {
    const float* emb = (const float*)d_in[0];
    const float* qry = (const float*)d_in[1];
    float* out = (float*)d_out;

    char* ws = (char*)d_ws;
    unsigned char* En = (unsigned char*)ws;                         // 2 MB fp8 row-major
    unsigned char* Qn = (unsigned char*)(ws + (size_t)NROWS * 256); // 2 MB fp8 K-major-grouped
    float* rowsum = (float*)(ws + (size_t)2 * NROWS * 256);         // 32 KB
    float* pickv  = rowsum + NROWS;                                 // 32 KB

    k_normalize_all<<<2 * NROWS / 4, 256, 0, stream>>>(emb, qry, En, Qn, rowsum, out);
    k_simlse<<<32 * NSPLIT, 256, 0, stream>>>(En, Qn, rowsum, pickv);
    k_finalize<<<16, 256, 0, stream>>>(rowsum, pickv, out);
}